// Round 1
// baseline (1491.732 us; speedup 1.0000x reference)
//
#include <hip/hip_runtime.h>

#define SEQ 2048
#define DMODEL 2048
#define NHEAD 16
#define EHEAD 128
#define NE3 384   // 3*EHEAD

using short8 = __attribute__((ext_vector_type(8))) short;
using f32x4  = __attribute__((ext_vector_type(4))) float;

__device__ __forceinline__ unsigned short f32_to_bf16(float f) {
    unsigned int u = __float_as_uint(f);
    unsigned int rounding = 0x7fffu + ((u >> 16) & 1u);
    u += rounding;
    return (unsigned short)(u >> 16);
}

// ---------------- cast x fp32 -> bf16 ----------------
__global__ void cast_x_kernel(const float* __restrict__ x, unsigned short* __restrict__ xb) {
    int i = (blockIdx.x * blockDim.x + threadIdx.x) * 4;
    float4 v = *(const float4*)(x + i);
    unsigned short o0 = f32_to_bf16(v.x), o1 = f32_to_bf16(v.y);
    unsigned short o2 = f32_to_bf16(v.z), o3 = f32_to_bf16(v.w);
    ushort4 o = make_ushort4(o0, o1, o2, o3);
    *(ushort4*)(xb + i) = o;
}

// ---------------- transpose + cast w: [H][D][3E] fp32 -> [H][3E][D] bf16 ----------------
__global__ void transpose_w_kernel(const float* __restrict__ w, unsigned short* __restrict__ wT) {
    __shared__ float tile[32][33];
    int h  = blockIdx.z;
    int d0 = blockIdx.x * 32;
    int n0 = blockIdx.y * 32;
    int tx = threadIdx.x, ty = threadIdx.y;
    // read w[h][d0+ty][n0+tx]  (coalesced along n)
    tile[ty][tx] = w[(size_t)(h * DMODEL + d0 + ty) * NE3 + n0 + tx];
    __syncthreads();
    // write wT[h][n0+ty][d0+tx] (coalesced along d)
    wT[(size_t)(h * NE3 + n0 + ty) * DMODEL + d0 + tx] = f32_to_bf16(tile[tx][ty]);
}

// ---------------- QKV projection GEMM ----------------
// C[h][s][n] = sum_d xb[s][d] * wT[h][n][d], n in [0,384)
// n<128 -> Q[h][s][n]; n<256 -> K[h][s][n-128]; else Vt[h][n-256][s]
__global__ void qkv_gemm_kernel(const unsigned short* __restrict__ xb,
                                const unsigned short* __restrict__ wT,
                                unsigned short* __restrict__ Q,
                                unsigned short* __restrict__ Kb,
                                unsigned short* __restrict__ Vt) {
    int wave = threadIdx.x >> 6;
    int lane = threadIdx.x & 63;
    int tile = blockIdx.x * 4 + wave;          // 128*24 = 3072 tiles per head
    int h = blockIdx.y;
    int tm = tile / 24, tn = tile % 24;
    int m0 = tm * 16, n0 = tn * 16;
    int r = lane & 15, q = lane >> 4;

    const unsigned short* arow = xb + (size_t)(m0 + r) * DMODEL + q * 8;
    const unsigned short* brow = wT + ((size_t)h * NE3 + n0 + r) * DMODEL + q * 8;

    f32x4 acc = {0.f, 0.f, 0.f, 0.f};
    for (int k0 = 0; k0 < DMODEL; k0 += 32) {
        short8 a = *(const short8*)(arow + k0);
        short8 b = *(const short8*)(brow + k0);
        acc = __builtin_amdgcn_mfma_f32_16x16x32_bf16(a, b, acc, 0, 0, 0);
    }
    int col = n0 + r;
#pragma unroll
    for (int reg = 0; reg < 4; reg++) {
        int row = m0 + q * 4 + reg;
        unsigned short bv = f32_to_bf16(acc[reg]);
        if (col < EHEAD)
            Q[((size_t)h * SEQ + row) * EHEAD + col] = bv;
        else if (col < 2 * EHEAD)
            Kb[((size_t)h * SEQ + row) * EHEAD + (col - EHEAD)] = bv;
        else
            Vt[((size_t)h * EHEAD + (col - 2 * EHEAD)) * SEQ + row] = bv;
    }
}

// ---------------- scores GEMM (per head): Sc[s][t] = Q[s]·K[t] / sqrt(E) ----------------
__global__ void scores_gemm_kernel(const unsigned short* __restrict__ Q,
                                   const unsigned short* __restrict__ Kb,
                                   float* __restrict__ Sc, int h) {
    int wave = threadIdx.x >> 6;
    int lane = threadIdx.x & 63;
    int tile = blockIdx.x * 4 + wave;          // 128*128 = 16384 tiles
    int tm = tile >> 7, tn = tile & 127;
    int m0 = tm * 16, n0 = tn * 16;
    int r = lane & 15, q = lane >> 4;

    const unsigned short* arow = Q + ((size_t)h * SEQ + m0 + r) * EHEAD + q * 8;
    const unsigned short* brow = Kb + ((size_t)h * SEQ + n0 + r) * EHEAD + q * 8;

    f32x4 acc = {0.f, 0.f, 0.f, 0.f};
#pragma unroll
    for (int k0 = 0; k0 < EHEAD; k0 += 32) {
        short8 a = *(const short8*)(arow + k0);
        short8 b = *(const short8*)(brow + k0);
        acc = __builtin_amdgcn_mfma_f32_16x16x32_bf16(a, b, acc, 0, 0, 0);
    }
    const float scale = 0.08838834764831845f;  // 1/sqrt(128)
#pragma unroll
    for (int reg = 0; reg < 4; reg++) {
        int row = m0 + q * 4 + reg;
        Sc[(size_t)row * SEQ + n0 + r] = acc[reg] * scale;
    }
}

// ---------------- row softmax (per head): P = softmax(Sc) in bf16 ----------------
__global__ void softmax_kernel(const float* __restrict__ Sc, unsigned short* __restrict__ P) {
    int row = blockIdx.x;
    const float* src = Sc + (size_t)row * SEQ;
    unsigned short* dst = P + (size_t)row * SEQ;
    int t = threadIdx.x;            // 256 threads, 8 elems each
    __shared__ float sred[8];

    float v[8];
    float mx = -1e30f;
#pragma unroll
    for (int j = 0; j < 8; j++) { v[j] = src[t + j * 256]; mx = fmaxf(mx, v[j]); }
#pragma unroll
    for (int off = 32; off > 0; off >>= 1) mx = fmaxf(mx, __shfl_down(mx, off));
    int wv = threadIdx.x >> 6;
    if ((threadIdx.x & 63) == 0) sred[wv] = mx;
    __syncthreads();
    if (threadIdx.x == 0) {
        float m = sred[0];
        for (int i = 1; i < 4; i++) m = fmaxf(m, sred[i]);
        sred[4] = m;
    }
    __syncthreads();
    mx = sred[4];

    float e[8];
    float sum = 0.f;
#pragma unroll
    for (int j = 0; j < 8; j++) { e[j] = __expf(v[j] - mx); sum += e[j]; }
#pragma unroll
    for (int off = 32; off > 0; off >>= 1) sum += __shfl_down(sum, off);
    __syncthreads();
    if ((threadIdx.x & 63) == 0) sred[wv] = sum;
    __syncthreads();
    if (threadIdx.x == 0) sred[4] = sred[0] + sred[1] + sred[2] + sred[3];
    __syncthreads();
    float inv = 1.0f / sred[4];
#pragma unroll
    for (int j = 0; j < 8; j++) dst[t + j * 256] = f32_to_bf16(e[j] * inv);
}

// ---------------- out GEMM (per head): out[s][h*E+e] = sum_t P[s][t] * Vt[e][t] ----------------
__global__ void out_gemm_kernel(const unsigned short* __restrict__ P,
                                const unsigned short* __restrict__ Vt,
                                float* __restrict__ out, int h) {
    int wave = threadIdx.x >> 6;
    int lane = threadIdx.x & 63;
    int tile = blockIdx.x * 4 + wave;          // 128*8 = 1024 tiles
    int tm = tile >> 3, tn = tile & 7;
    int m0 = tm * 16, n0 = tn * 16;
    int r = lane & 15, q = lane >> 4;

    const unsigned short* arow = P + (size_t)(m0 + r) * SEQ + q * 8;
    const unsigned short* brow = Vt + ((size_t)h * EHEAD + n0 + r) * SEQ + q * 8;

    f32x4 acc = {0.f, 0.f, 0.f, 0.f};
    for (int k0 = 0; k0 < SEQ; k0 += 32) {
        short8 a = *(const short8*)(arow + k0);
        short8 b = *(const short8*)(brow + k0);
        acc = __builtin_amdgcn_mfma_f32_16x16x32_bf16(a, b, acc, 0, 0, 0);
    }
#pragma unroll
    for (int reg = 0; reg < 4; reg++) {
        int row = m0 + q * 4 + reg;
        out[(size_t)row * DMODEL + h * EHEAD + n0 + r] = acc[reg];
    }
}

extern "C" void kernel_launch(void* const* d_in, const int* in_sizes, int n_in,
                              void* d_out, int out_size, void* d_ws, size_t ws_size,
                              hipStream_t stream) {
    const float* x = (const float*)d_in[0];      // [S][D]
    const float* w = (const float*)d_in[1];      // [H][D][3E]
    float* out = (float*)d_out;                  // [S][H*E]

    // workspace layout (bytes)
    char* ws = (char*)d_ws;
    unsigned short* xb = (unsigned short*)(ws);                        //  8 MB  [S][D] bf16
    unsigned short* wT = (unsigned short*)(ws + 8388608);              // 25 MB  [H][3E][D] bf16
    unsigned short* Q  = (unsigned short*)(ws + 33554432);             //  8 MB  [H][S][E]
    unsigned short* Kb = (unsigned short*)(ws + 41943040);             //  8 MB  [H][S][E]
    unsigned short* Vt = (unsigned short*)(ws + 50331648);             //  8 MB  [H][E][S]
    float*          Sc = (float*)(ws + 58720256);                      // 16 MB  [S][S] fp32 (reused per head)
    unsigned short* P  = (unsigned short*)(ws + 75497472);             //  8 MB  [S][S] bf16 (reused per head)

    // 1. cast x
    cast_x_kernel<<<SEQ * DMODEL / (256 * 4), 256, 0, stream>>>(x, xb);
    // 2. transpose + cast w
    transpose_w_kernel<<<dim3(DMODEL / 32, NE3 / 32, NHEAD), dim3(32, 32), 0, stream>>>(w, wT);
    // 3. QKV projection
    qkv_gemm_kernel<<<dim3(3072 / 4, NHEAD), 256, 0, stream>>>(xb, wT, Q, Kb, Vt);
    // 4. per-head attention (stream-serialized; Sc/P buffers reused)
    for (int h = 0; h < NHEAD; h++) {
        scores_gemm_kernel<<<16384 / 4, 256, 0, stream>>>(Q, Kb, Sc, h);
        softmax_kernel<<<SEQ, 256, 0, stream>>>(Sc, P);
        out_gemm_kernel<<<1024 / 4, 256, 0, stream>>>(P, Vt, out, h);
    }
}

// Round 2
// 741.025 us; speedup vs baseline: 2.0131x; 2.0131x over previous
//
#include <hip/hip_runtime.h>

#define SEQ 2048
#define DMODEL 2048
#define NHEAD 16
#define EHEAD 128
#define NE3 384   // 3*EHEAD

using short8 = __attribute__((ext_vector_type(8))) short;
using f32x4  = __attribute__((ext_vector_type(4))) float;

__device__ __forceinline__ unsigned short f32_to_bf16(float f) {
    unsigned int u = __float_as_uint(f);
    unsigned int rounding = 0x7fffu + ((u >> 16) & 1u);
    u += rounding;
    return (unsigned short)(u >> 16);
}

// async global->LDS, 16B per lane; lds ptr must be wave-uniform base
__device__ __forceinline__ void async_load16(const void* g, void* l) {
    __builtin_amdgcn_global_load_lds(
        (const __attribute__((address_space(1))) unsigned int*)g,
        (__attribute__((address_space(3))) unsigned int*)l, 16, 0, 0);
}

// ---------------- cast x fp32 -> bf16 ----------------
__global__ void cast_x_kernel(const float* __restrict__ x, unsigned short* __restrict__ xb) {
    int i = (blockIdx.x * blockDim.x + threadIdx.x) * 4;
    float4 v = *(const float4*)(x + i);
    ushort4 o = make_ushort4(f32_to_bf16(v.x), f32_to_bf16(v.y), f32_to_bf16(v.z), f32_to_bf16(v.w));
    *(ushort4*)(xb + i) = o;
}

// ---------------- transpose + cast w: [H][D][3E] fp32 -> [H][3E][D] bf16 ----------------
__global__ void transpose_w_kernel(const float* __restrict__ w, unsigned short* __restrict__ wT) {
    __shared__ float tile[32][33];
    int h  = blockIdx.z;
    int d0 = blockIdx.x * 32;
    int n0 = blockIdx.y * 32;
    int tx = threadIdx.x, ty = threadIdx.y;
    tile[ty][tx] = w[(size_t)(h * DMODEL + d0 + ty) * NE3 + n0 + tx];
    __syncthreads();
    wT[(size_t)(h * NE3 + n0 + ty) * DMODEL + d0 + tx] = f32_to_bf16(tile[tx][ty]);
}

// ---------------- QKV projection: m97-style 128x128 tile GEMM ----------------
// C[s][nb*128+c] over A=xb[2048][2048], B=wT[6144][2048] (flattened [H][3E]).
// nb%3 selects Q / K / V(transposed store).
__global__ __launch_bounds__(256, 2) void qkv_gemm128(
        const unsigned short* __restrict__ A,
        const unsigned short* __restrict__ B,
        unsigned short* __restrict__ Q,
        unsigned short* __restrict__ Kb,
        unsigned short* __restrict__ Vt) {
    __shared__ __attribute__((aligned(16))) unsigned short sA[128 * 32];
    __shared__ __attribute__((aligned(16))) unsigned short sB[128 * 32];
    const int mb = blockIdx.x, nb = blockIdx.y;
    const int tid = threadIdx.x;
    const int wave = tid >> 6, lane = tid & 63;
    const int r = lane & 15, q = lane >> 4;
    const int wm = wave & 1, wn = wave >> 1;

    const unsigned short* gA0 = A + (size_t)(mb * 128 + (tid >> 2)) * DMODEL + (tid & 3) * 8;
    const unsigned short* gA1 = gA0 + (size_t)64 * DMODEL;
    const unsigned short* gB0 = B + (size_t)(nb * 128 + (tid >> 2)) * DMODEL + (tid & 3) * 8;
    const unsigned short* gB1 = gB0 + (size_t)64 * DMODEL;
    unsigned short* lA0 = sA + wave * 512;          // bytes: wave*1024
    unsigned short* lA1 = sA + 2048 + wave * 512;   // second 64 rows
    unsigned short* lB0 = sB + wave * 512;
    unsigned short* lB1 = sB + 2048 + wave * 512;

    f32x4 acc[4][4] = {};
    for (int k0 = 0; k0 < DMODEL; k0 += 32) {
        __syncthreads();
        async_load16(gA0 + k0, lA0);
        async_load16(gA1 + k0, lA1);
        async_load16(gB0 + k0, lB0);
        async_load16(gB1 + k0, lB1);
        __syncthreads();
        short8 a[4], b[4];
#pragma unroll
        for (int i = 0; i < 4; i++) a[i] = *(const short8*)&sA[(wm * 64 + i * 16 + r) * 32 + q * 8];
#pragma unroll
        for (int j = 0; j < 4; j++) b[j] = *(const short8*)&sB[(wn * 64 + j * 16 + r) * 32 + q * 8];
#pragma unroll
        for (int i = 0; i < 4; i++)
#pragma unroll
            for (int j = 0; j < 4; j++)
                acc[i][j] = __builtin_amdgcn_mfma_f32_16x16x32_bf16(a[i], b[j], acc[i][j], 0, 0, 0);
    }

    const int h = nb / 3, sel = nb % 3;
#pragma unroll
    for (int i = 0; i < 4; i++) {
#pragma unroll
        for (int j = 0; j < 4; j++) {
            const int row0 = mb * 128 + wm * 64 + i * 16 + q * 4;
            const int col  = wn * 64 + j * 16 + r;
            if (sel == 2) {
                ushort4 v;
                v.x = f32_to_bf16(acc[i][j][0]);
                v.y = f32_to_bf16(acc[i][j][1]);
                v.z = f32_to_bf16(acc[i][j][2]);
                v.w = f32_to_bf16(acc[i][j][3]);
                *(ushort4*)&Vt[((size_t)h * EHEAD + col) * SEQ + row0] = v;
            } else {
                unsigned short* dst = (sel == 0) ? Q : Kb;
#pragma unroll
                for (int reg = 0; reg < 4; reg++)
                    dst[((size_t)h * SEQ + row0 + reg) * EHEAD + col] = f32_to_bf16(acc[i][j][reg]);
            }
        }
    }
}

// ---------------- scores (per head): Sc = Q K^T / sqrt(E), 128x128 tiles ----------------
__global__ __launch_bounds__(256, 2) void scores_gemm128(
        const unsigned short* __restrict__ Qg,
        const unsigned short* __restrict__ Kg,
        float* __restrict__ Sc, int h) {
    __shared__ __attribute__((aligned(16))) unsigned short sA[128 * 32];
    __shared__ __attribute__((aligned(16))) unsigned short sB[128 * 32];
    const int mb = blockIdx.x, nb = blockIdx.y;
    const int tid = threadIdx.x;
    const int wave = tid >> 6, lane = tid & 63;
    const int r = lane & 15, q = lane >> 4;
    const int wm = wave & 1, wn = wave >> 1;

    const unsigned short* A = Qg + (size_t)h * SEQ * EHEAD;
    const unsigned short* B = Kg + (size_t)h * SEQ * EHEAD;
    const unsigned short* gA0 = A + (size_t)(mb * 128 + (tid >> 2)) * EHEAD + (tid & 3) * 8;
    const unsigned short* gA1 = gA0 + (size_t)64 * EHEAD;
    const unsigned short* gB0 = B + (size_t)(nb * 128 + (tid >> 2)) * EHEAD + (tid & 3) * 8;
    const unsigned short* gB1 = gB0 + (size_t)64 * EHEAD;
    unsigned short* lA0 = sA + wave * 512;
    unsigned short* lA1 = sA + 2048 + wave * 512;
    unsigned short* lB0 = sB + wave * 512;
    unsigned short* lB1 = sB + 2048 + wave * 512;

    f32x4 acc[4][4] = {};
#pragma unroll
    for (int k0 = 0; k0 < EHEAD; k0 += 32) {
        __syncthreads();
        async_load16(gA0 + k0, lA0);
        async_load16(gA1 + k0, lA1);
        async_load16(gB0 + k0, lB0);
        async_load16(gB1 + k0, lB1);
        __syncthreads();
        short8 a[4], b[4];
#pragma unroll
        for (int i = 0; i < 4; i++) a[i] = *(const short8*)&sA[(wm * 64 + i * 16 + r) * 32 + q * 8];
#pragma unroll
        for (int j = 0; j < 4; j++) b[j] = *(const short8*)&sB[(wn * 64 + j * 16 + r) * 32 + q * 8];
#pragma unroll
        for (int i = 0; i < 4; i++)
#pragma unroll
            for (int j = 0; j < 4; j++)
                acc[i][j] = __builtin_amdgcn_mfma_f32_16x16x32_bf16(a[i], b[j], acc[i][j], 0, 0, 0);
    }

    const float scale = 0.08838834764831845f;  // 1/sqrt(128)
#pragma unroll
    for (int i = 0; i < 4; i++)
#pragma unroll
        for (int j = 0; j < 4; j++) {
            const int row0 = mb * 128 + wm * 64 + i * 16 + q * 4;
            const int col  = nb * 128 + wn * 64 + j * 16 + r;
#pragma unroll
            for (int reg = 0; reg < 4; reg++)
                Sc[(size_t)(row0 + reg) * SEQ + col] = acc[i][j][reg] * scale;
        }
}

// ---------------- row softmax (per head): P = softmax(Sc) in bf16 ----------------
__global__ void softmax_kernel(const float* __restrict__ Sc, unsigned short* __restrict__ P) {
    int row = blockIdx.x;
    const float* src = Sc + (size_t)row * SEQ;
    unsigned short* dst = P + (size_t)row * SEQ;
    int t = threadIdx.x;
    __shared__ float sred[8];

    float v[8];
    float mx = -1e30f;
#pragma unroll
    for (int j = 0; j < 8; j++) { v[j] = src[t + j * 256]; mx = fmaxf(mx, v[j]); }
#pragma unroll
    for (int off = 32; off > 0; off >>= 1) mx = fmaxf(mx, __shfl_down(mx, off));
    int wv = threadIdx.x >> 6;
    if ((threadIdx.x & 63) == 0) sred[wv] = mx;
    __syncthreads();
    if (threadIdx.x == 0) {
        float m = sred[0];
        for (int i = 1; i < 4; i++) m = fmaxf(m, sred[i]);
        sred[4] = m;
    }
    __syncthreads();
    mx = sred[4];

    float e[8];
    float sum = 0.f;
#pragma unroll
    for (int j = 0; j < 8; j++) { e[j] = __expf(v[j] - mx); sum += e[j]; }
#pragma unroll
    for (int off = 32; off > 0; off >>= 1) sum += __shfl_down(sum, off);
    __syncthreads();
    if ((threadIdx.x & 63) == 0) sred[wv] = sum;
    __syncthreads();
    if (threadIdx.x == 0) sred[4] = sred[0] + sred[1] + sred[2] + sred[3];
    __syncthreads();
    float inv = 1.0f / sred[4];
#pragma unroll
    for (int j = 0; j < 8; j++) dst[t + j * 256] = f32_to_bf16(e[j] * inv);
}

// ---------------- out (per head): out[s][h*E+e] += P V, K-split x8, atomics ----------------
__global__ __launch_bounds__(256, 2) void out_gemm128(
        const unsigned short* __restrict__ P,
        const unsigned short* __restrict__ Vt,
        float* __restrict__ out, int h) {
    __shared__ __attribute__((aligned(16))) unsigned short sA[128 * 32];
    __shared__ __attribute__((aligned(16))) unsigned short sB[128 * 32];
    const int mb = blockIdx.x, ks = blockIdx.y;   // ks in [0,8): K-chunk of 256
    const int tid = threadIdx.x;
    const int wave = tid >> 6, lane = tid & 63;
    const int r = lane & 15, q = lane >> 4;
    const int wm = wave & 1, wn = wave >> 1;

    const unsigned short* B = Vt + (size_t)h * EHEAD * SEQ;
    const unsigned short* gA0 = P + (size_t)(mb * 128 + (tid >> 2)) * SEQ + ks * 256 + (tid & 3) * 8;
    const unsigned short* gA1 = gA0 + (size_t)64 * SEQ;
    const unsigned short* gB0 = B + (size_t)(tid >> 2) * SEQ + ks * 256 + (tid & 3) * 8;
    const unsigned short* gB1 = gB0 + (size_t)64 * SEQ;
    unsigned short* lA0 = sA + wave * 512;
    unsigned short* lA1 = sA + 2048 + wave * 512;
    unsigned short* lB0 = sB + wave * 512;
    unsigned short* lB1 = sB + 2048 + wave * 512;

    f32x4 acc[4][4] = {};
#pragma unroll 2
    for (int k0 = 0; k0 < 256; k0 += 32) {
        __syncthreads();
        async_load16(gA0 + k0, lA0);
        async_load16(gA1 + k0, lA1);
        async_load16(gB0 + k0, lB0);
        async_load16(gB1 + k0, lB1);
        __syncthreads();
        short8 a[4], b[4];
#pragma unroll
        for (int i = 0; i < 4; i++) a[i] = *(const short8*)&sA[(wm * 64 + i * 16 + r) * 32 + q * 8];
#pragma unroll
        for (int j = 0; j < 4; j++) b[j] = *(const short8*)&sB[(wn * 64 + j * 16 + r) * 32 + q * 8];
#pragma unroll
        for (int i = 0; i < 4; i++)
#pragma unroll
            for (int j = 0; j < 4; j++)
                acc[i][j] = __builtin_amdgcn_mfma_f32_16x16x32_bf16(a[i], b[j], acc[i][j], 0, 0, 0);
    }

#pragma unroll
    for (int i = 0; i < 4; i++)
#pragma unroll
        for (int j = 0; j < 4; j++) {
            const int row0 = mb * 128 + wm * 64 + i * 16 + q * 4;
            const int col  = wn * 64 + j * 16 + r;   // e index, [0,128)
#pragma unroll
            for (int reg = 0; reg < 4; reg++)
                atomicAdd(&out[(size_t)(row0 + reg) * DMODEL + h * EHEAD + col], acc[i][j][reg]);
        }
}

extern "C" void kernel_launch(void* const* d_in, const int* in_sizes, int n_in,
                              void* d_out, int out_size, void* d_ws, size_t ws_size,
                              hipStream_t stream) {
    const float* x = (const float*)d_in[0];      // [S][D]
    const float* w = (const float*)d_in[1];      // [H][D][3E]
    float* out = (float*)d_out;                  // [S][H*E]

    char* ws = (char*)d_ws;
    unsigned short* xb = (unsigned short*)(ws);                        //  8 MB
    unsigned short* wT = (unsigned short*)(ws + 8388608);              // 24 MB
    unsigned short* Q  = (unsigned short*)(ws + 33554432);             //  8 MB
    unsigned short* Kb = (unsigned short*)(ws + 41943040);             //  8 MB
    unsigned short* Vt = (unsigned short*)(ws + 50331648);             //  8 MB
    float*          Sc = (float*)(ws + 58720256);                      // 16 MB (per-head reuse)
    unsigned short* P  = (unsigned short*)(ws + 75497472);             //  8 MB (per-head reuse)

    hipMemsetAsync(d_out, 0, (size_t)SEQ * DMODEL * sizeof(float), stream);
    cast_x_kernel<<<SEQ * DMODEL / (256 * 4), 256, 0, stream>>>(x, xb);
    transpose_w_kernel<<<dim3(DMODEL / 32, NE3 / 32, NHEAD), dim3(32, 32), 0, stream>>>(w, wT);
    qkv_gemm128<<<dim3(SEQ / 128, (NHEAD * NE3) / 128), 256, 0, stream>>>(xb, wT, Q, Kb, Vt);
    for (int h = 0; h < NHEAD; h++) {
        scores_gemm128<<<dim3(SEQ / 128, SEQ / 128), 256, 0, stream>>>(Q, Kb, Sc, h);
        softmax_kernel<<<SEQ, 256, 0, stream>>>(Sc, P);
        out_gemm128<<<dim3(SEQ / 128, 8), 256, 0, stream>>>(P, Vt, out, h);
    }
}

// Round 3
// 258.560 us; speedup vs baseline: 5.7694x; 2.8660x over previous
//
#include <hip/hip_runtime.h>

#define SEQ 2048
#define DMODEL 2048
#define NHEAD 16
#define EHEAD 128
#define NE3 384   // 3*EHEAD

using short8 = __attribute__((ext_vector_type(8))) short;
using f32x4  = __attribute__((ext_vector_type(4))) float;

__device__ __forceinline__ unsigned short f32_to_bf16(float f) {
    unsigned int u = __float_as_uint(f);
    unsigned int rounding = 0x7fffu + ((u >> 16) & 1u);
    u += rounding;
    return (unsigned short)(u >> 16);
}

// async global->LDS, 16B per lane; lds ptr must be wave-uniform base (HW writes base + lane*16)
__device__ __forceinline__ void async_load16(const void* g, void* l) {
    __builtin_amdgcn_global_load_lds(
        (const __attribute__((address_space(1))) unsigned int*)g,
        (__attribute__((address_space(3))) unsigned int*)l, 16, 0, 0);
}

// ---------------- cast x fp32 -> bf16 ----------------
__global__ void cast_x_kernel(const float* __restrict__ x, unsigned short* __restrict__ xb) {
    int i = (blockIdx.x * blockDim.x + threadIdx.x) * 4;
    float4 v = *(const float4*)(x + i);
    ushort4 o = make_ushort4(f32_to_bf16(v.x), f32_to_bf16(v.y), f32_to_bf16(v.z), f32_to_bf16(v.w));
    *(ushort4*)(xb + i) = o;
}

// ---------------- transpose + cast w: [H][D][3E] fp32 -> [H][3E][D] bf16 ----------------
__global__ void transpose_w_kernel(const float* __restrict__ w, unsigned short* __restrict__ wT) {
    __shared__ float tile[32][33];
    int h  = blockIdx.z;
    int d0 = blockIdx.x * 32;
    int n0 = blockIdx.y * 32;
    int tx = threadIdx.x, ty = threadIdx.y;
    tile[ty][tx] = w[(size_t)(h * DMODEL + d0 + ty) * NE3 + n0 + tx];
    __syncthreads();
    wT[(size_t)(h * NE3 + n0 + ty) * DMODEL + d0 + tx] = f32_to_bf16(tile[tx][ty]);
}

// ---------------- QKV projection: m97-style 128x128 tile GEMM ----------------
__global__ __launch_bounds__(256, 2) void qkv_gemm128(
        const unsigned short* __restrict__ A,
        const unsigned short* __restrict__ B,
        unsigned short* __restrict__ Q,
        unsigned short* __restrict__ Kb,
        unsigned short* __restrict__ Vt) {
    __shared__ __attribute__((aligned(16))) unsigned short sA[128 * 32];
    __shared__ __attribute__((aligned(16))) unsigned short sB[128 * 32];
    const int mb = blockIdx.x, nb = blockIdx.y;
    const int tid = threadIdx.x;
    const int wave = tid >> 6, lane = tid & 63;
    const int r = lane & 15, q = lane >> 4;
    const int wm = wave & 1, wn = wave >> 1;

    const unsigned short* gA0 = A + (size_t)(mb * 128 + (tid >> 2)) * DMODEL + (tid & 3) * 8;
    const unsigned short* gA1 = gA0 + (size_t)64 * DMODEL;
    const unsigned short* gB0 = B + (size_t)(nb * 128 + (tid >> 2)) * DMODEL + (tid & 3) * 8;
    const unsigned short* gB1 = gB0 + (size_t)64 * DMODEL;
    unsigned short* lA0 = sA + wave * 512;
    unsigned short* lA1 = sA + 2048 + wave * 512;
    unsigned short* lB0 = sB + wave * 512;
    unsigned short* lB1 = sB + 2048 + wave * 512;

    f32x4 acc[4][4] = {};
    for (int k0 = 0; k0 < DMODEL; k0 += 32) {
        __syncthreads();
        async_load16(gA0 + k0, lA0);
        async_load16(gA1 + k0, lA1);
        async_load16(gB0 + k0, lB0);
        async_load16(gB1 + k0, lB1);
        __syncthreads();
        short8 a[4], b[4];
#pragma unroll
        for (int i = 0; i < 4; i++) a[i] = *(const short8*)&sA[(wm * 64 + i * 16 + r) * 32 + q * 8];
#pragma unroll
        for (int j = 0; j < 4; j++) b[j] = *(const short8*)&sB[(wn * 64 + j * 16 + r) * 32 + q * 8];
#pragma unroll
        for (int i = 0; i < 4; i++)
#pragma unroll
            for (int j = 0; j < 4; j++)
                acc[i][j] = __builtin_amdgcn_mfma_f32_16x16x32_bf16(a[i], b[j], acc[i][j], 0, 0, 0);
    }

    const int h = nb / 3, sel = nb % 3;
#pragma unroll
    for (int i = 0; i < 4; i++) {
#pragma unroll
        for (int j = 0; j < 4; j++) {
            const int row0 = mb * 128 + wm * 64 + i * 16 + q * 4;
            const int col  = wn * 64 + j * 16 + r;
            if (sel == 2) {
                ushort4 v;
                v.x = f32_to_bf16(acc[i][j][0]);
                v.y = f32_to_bf16(acc[i][j][1]);
                v.z = f32_to_bf16(acc[i][j][2]);
                v.w = f32_to_bf16(acc[i][j][3]);
                *(ushort4*)&Vt[((size_t)h * EHEAD + col) * SEQ + row0] = v;
            } else {
                unsigned short* dst = (sel == 0) ? Q : Kb;
#pragma unroll
                for (int reg = 0; reg < 4; reg++)
                    dst[((size_t)h * SEQ + row0 + reg) * EHEAD + col] = f32_to_bf16(acc[i][j][reg]);
            }
        }
    }
}

// ---------------- fused flash attention ----------------
// grid (SEQ/64, NHEAD); block 256 = 4 waves, wave w owns Q rows [w*16, w*16+16).
// Per iter: 64-key tile. S = Q K^T (MFMA), online softmax, P->LDS, O += P V.
__global__ __launch_bounds__(256, 2) void flash_attn(
        const unsigned short* __restrict__ Qg,
        const unsigned short* __restrict__ Kg,
        const unsigned short* __restrict__ Vtg,
        float* __restrict__ out) {
    // LDS: sQ [4 kc][64 rows][32] = 16KB (reused as P after prologue)
    //      sK [4 kc][64 rows][32] = 16KB ; sV [2 tc][128 e][32] = 16KB
    __shared__ __attribute__((aligned(16))) unsigned short lds[24576];
    unsigned short* sQ = lds;
    unsigned short* sK = lds + 8192;
    unsigned short* sV = lds + 16384;

    const int tid = threadIdx.x;
    const int wave = tid >> 6, lane = tid & 63;
    const int r = lane & 15, q = lane >> 4;
    const int h = blockIdx.y;
    const int m0 = blockIdx.x * 64;

    const unsigned short* Qh  = Qg  + ((size_t)h * SEQ + m0) * EHEAD;
    const unsigned short* Kh0 = Kg  + (size_t)h * SEQ * EHEAD;
    const unsigned short* Vh  = Vtg + (size_t)h * EHEAD * SEQ;

    // ---- prologue: stage Q tile, load resident A-fragments ----
#pragma unroll
    for (int c = 0; c < 4; c++)
        async_load16(Qh + (size_t)(tid >> 2) * EHEAD + c * 32 + (tid & 3) * 8,
                     sQ + c * 2048 + wave * 512);
    __syncthreads();
    short8 aq[4];
#pragma unroll
    for (int k = 0; k < 4; k++)
        aq[k] = *(const short8*)&sQ[k * 2048 + (wave * 16 + r) * 32 + q * 8];
    // P region (aliases sQ) — per-wave private [2 tk][16 m][32]
    unsigned short* sP = sQ + wave * 1024;

    const float scale = 0.08838834764831845f;  // 1/sqrt(128)
    f32x4 acc_o[8] = {};
    float m_i[4] = {-1e30f, -1e30f, -1e30f, -1e30f};
    float l_i[4] = {};

    for (int it = 0; it < SEQ / 64; it++) {
        const unsigned short* Kh = Kh0 + (size_t)(it * 64) * EHEAD;
        __syncthreads();   // all waves done reading sK/sV (and, iter 0, sQ frags)
#pragma unroll
        for (int c = 0; c < 4; c++)
            async_load16(Kh + (size_t)(tid >> 2) * EHEAD + c * 32 + (tid & 3) * 8,
                         sK + c * 2048 + wave * 512);
#pragma unroll
        for (int c = 0; c < 4; c++)
            async_load16(Vh + (size_t)((c & 1) * 64 + (tid >> 2)) * SEQ + it * 64 + (c >> 1) * 32 + (tid & 3) * 8,
                         sV + (c >> 1) * 4096 + (c & 1) * 2048 + wave * 512);
        __syncthreads();   // drain staging

        // ---- S = Q K^T over this 64-key tile: s[j] covers keys j*16..j*16+15 ----
        f32x4 s[4] = {};
#pragma unroll
        for (int j = 0; j < 4; j++)
#pragma unroll
            for (int k = 0; k < 4; k++) {
                short8 b = *(const short8*)&sK[k * 2048 + (j * 16 + r) * 32 + q * 8];
                s[j] = __builtin_amdgcn_mfma_f32_16x16x32_bf16(aq[k], b, s[j], 0, 0, 0);
            }

        // ---- online softmax (rows = q*4+reg within wave's 16) ----
#pragma unroll
        for (int reg = 0; reg < 4; reg++) {
            float mx = fmaxf(fmaxf(s[0][reg], s[1][reg]), fmaxf(s[2][reg], s[3][reg])) * scale;
            mx = fmaxf(mx, __shfl_xor(mx, 1));
            mx = fmaxf(mx, __shfl_xor(mx, 2));
            mx = fmaxf(mx, __shfl_xor(mx, 4));
            mx = fmaxf(mx, __shfl_xor(mx, 8));
            float mnew = fmaxf(m_i[reg], mx);
            float alpha = __expf(m_i[reg] - mnew);
            m_i[reg] = mnew;
            float rsum = 0.f;
#pragma unroll
            for (int j = 0; j < 4; j++) {
                float p = __expf(s[j][reg] * scale - mnew);
                s[j][reg] = p;
                rsum += p;
            }
            rsum += __shfl_xor(rsum, 1);
            rsum += __shfl_xor(rsum, 2);
            rsum += __shfl_xor(rsum, 4);
            rsum += __shfl_xor(rsum, 8);
            l_i[reg] = l_i[reg] * alpha + rsum;
#pragma unroll
            for (int j = 0; j < 8; j++) acc_o[j][reg] *= alpha;
        }

        // ---- P -> LDS (C-layout -> A-layout round trip, per-wave private) ----
#pragma unroll
        for (int j = 0; j < 4; j++)
#pragma unroll
            for (int reg = 0; reg < 4; reg++)
                sP[(j >> 1) * 512 + (q * 4 + reg) * 32 + (j & 1) * 16 + r] = f32_to_bf16(s[j][reg]);

        short8 ap[2];
#pragma unroll
        for (int tk = 0; tk < 2; tk++)
            ap[tk] = *(const short8*)&sP[tk * 512 + r * 32 + q * 8];

        // ---- O += P V ----
#pragma unroll
        for (int j = 0; j < 8; j++)
#pragma unroll
            for (int tk = 0; tk < 2; tk++) {
                short8 bv = *(const short8*)&sV[tk * 4096 + (j * 16 + r) * 32 + q * 8];
                acc_o[j] = __builtin_amdgcn_mfma_f32_16x16x32_bf16(ap[tk], bv, acc_o[j], 0, 0, 0);
            }
    }

    // ---- epilogue: normalize + store fp32 ----
    float inv[4];
#pragma unroll
    for (int reg = 0; reg < 4; reg++) inv[reg] = 1.0f / l_i[reg];
#pragma unroll
    for (int j = 0; j < 8; j++)
#pragma unroll
        for (int reg = 0; reg < 4; reg++)
            out[(size_t)(m0 + wave * 16 + q * 4 + reg) * DMODEL + h * EHEAD + j * 16 + r] =
                acc_o[j][reg] * inv[reg];
}

extern "C" void kernel_launch(void* const* d_in, const int* in_sizes, int n_in,
                              void* d_out, int out_size, void* d_ws, size_t ws_size,
                              hipStream_t stream) {
    const float* x = (const float*)d_in[0];      // [S][D]
    const float* w = (const float*)d_in[1];      // [H][D][3E]
    float* out = (float*)d_out;                  // [S][H*E]

    char* ws = (char*)d_ws;
    unsigned short* xb = (unsigned short*)(ws);                        //  8 MB
    unsigned short* wT = (unsigned short*)(ws + 8388608);              // 24 MB
    unsigned short* Q  = (unsigned short*)(ws + 33554432);             //  8 MB
    unsigned short* Kb = (unsigned short*)(ws + 41943040);             //  8 MB
    unsigned short* Vt = (unsigned short*)(ws + 50331648);             //  8 MB

    cast_x_kernel<<<SEQ * DMODEL / (256 * 4), 256, 0, stream>>>(x, xb);
    transpose_w_kernel<<<dim3(DMODEL / 32, NE3 / 32, NHEAD), dim3(32, 32), 0, stream>>>(w, wT);
    qkv_gemm128<<<dim3(SEQ / 128, (NHEAD * NE3) / 128), 256, 0, stream>>>(xb, wT, Q, Kb, Vt);
    flash_attn<<<dim3(SEQ / 64, NHEAD), 256, 0, stream>>>(Q, Kb, Vt, out);
}

// Round 4
// 249.164 us; speedup vs baseline: 5.9869x; 1.0377x over previous
//
#include <hip/hip_runtime.h>

#define SEQ 2048
#define DMODEL 2048
#define NHEAD 16
#define EHEAD 128
#define NE3 384   // 3*EHEAD

using short8 = __attribute__((ext_vector_type(8))) short;
using f32x4  = __attribute__((ext_vector_type(4))) float;

__device__ __forceinline__ unsigned short f32_to_bf16(float f) {
    unsigned int u = __float_as_uint(f);
    unsigned int rounding = 0x7fffu + ((u >> 16) & 1u);
    u += rounding;
    return (unsigned short)(u >> 16);
}

// async global->LDS, 16B per lane; lds ptr must be wave-uniform base (HW writes base + lane*16)
__device__ __forceinline__ void async_load16(const void* g, void* l) {
    __builtin_amdgcn_global_load_lds(
        (const __attribute__((address_space(1))) unsigned int*)g,
        (__attribute__((address_space(3))) unsigned int*)l, 16, 0, 0);
}

// ---------------- cast x fp32 -> bf16 ----------------
__global__ void cast_x_kernel(const float* __restrict__ x, unsigned short* __restrict__ xb) {
    int i = (blockIdx.x * blockDim.x + threadIdx.x) * 4;
    float4 v = *(const float4*)(x + i);
    ushort4 o = make_ushort4(f32_to_bf16(v.x), f32_to_bf16(v.y), f32_to_bf16(v.z), f32_to_bf16(v.w));
    *(ushort4*)(xb + i) = o;
}

// ---------------- transpose + cast w: [H][D][3E] fp32 -> [H][3E][D] bf16 ----------------
// 64x64 tile, float4 reads, ushort4 writes.
__global__ void transpose_w_kernel(const float* __restrict__ w, unsigned short* __restrict__ wT) {
    __shared__ float tile[64][65];
    int h  = blockIdx.z;
    int d0 = blockIdx.x * 64;
    int n0 = blockIdx.y * 64;
    int t = threadIdx.x;
    int rr = t >> 4;           // 0..15
    int cc = (t & 15) * 4;     // 0..60
#pragma unroll
    for (int i = 0; i < 4; i++) {
        float4 v = *(const float4*)&w[(size_t)(h * DMODEL + d0 + rr + i * 16) * NE3 + n0 + cc];
        tile[rr + i * 16][cc + 0] = v.x;
        tile[rr + i * 16][cc + 1] = v.y;
        tile[rr + i * 16][cc + 2] = v.z;
        tile[rr + i * 16][cc + 3] = v.w;
    }
    __syncthreads();
#pragma unroll
    for (int i = 0; i < 4; i++) {
        int n = rr + i * 16;
        ushort4 o;
        o.x = f32_to_bf16(tile[cc + 0][n]);
        o.y = f32_to_bf16(tile[cc + 1][n]);
        o.z = f32_to_bf16(tile[cc + 2][n]);
        o.w = f32_to_bf16(tile[cc + 3][n]);
        *(ushort4*)&wT[(size_t)(h * NE3 + n0 + n) * DMODEL + d0 + cc] = o;
    }
}

// ---------------- QKV projection: m97-style 128x128 tile GEMM ----------------
__global__ __launch_bounds__(256, 2) void qkv_gemm128(
        const unsigned short* __restrict__ A,
        const unsigned short* __restrict__ B,
        unsigned short* __restrict__ Q,
        unsigned short* __restrict__ Kb,
        unsigned short* __restrict__ Vt) {
    __shared__ __attribute__((aligned(16))) unsigned short sA[128 * 32];
    __shared__ __attribute__((aligned(16))) unsigned short sB[128 * 32];
    const int mb = blockIdx.x, nb = blockIdx.y;
    const int tid = threadIdx.x;
    const int wave = tid >> 6, lane = tid & 63;
    const int r = lane & 15, q = lane >> 4;
    const int wm = wave & 1, wn = wave >> 1;

    const unsigned short* gA0 = A + (size_t)(mb * 128 + (tid >> 2)) * DMODEL + (tid & 3) * 8;
    const unsigned short* gA1 = gA0 + (size_t)64 * DMODEL;
    const unsigned short* gB0 = B + (size_t)(nb * 128 + (tid >> 2)) * DMODEL + (tid & 3) * 8;
    const unsigned short* gB1 = gB0 + (size_t)64 * DMODEL;
    unsigned short* lA0 = sA + wave * 512;
    unsigned short* lA1 = sA + 2048 + wave * 512;
    unsigned short* lB0 = sB + wave * 512;
    unsigned short* lB1 = sB + 2048 + wave * 512;

    f32x4 acc[4][4] = {};
    for (int k0 = 0; k0 < DMODEL; k0 += 32) {
        __syncthreads();
        async_load16(gA0 + k0, lA0);
        async_load16(gA1 + k0, lA1);
        async_load16(gB0 + k0, lB0);
        async_load16(gB1 + k0, lB1);
        __syncthreads();
        short8 a[4], b[4];
#pragma unroll
        for (int i = 0; i < 4; i++) a[i] = *(const short8*)&sA[(wm * 64 + i * 16 + r) * 32 + q * 8];
#pragma unroll
        for (int j = 0; j < 4; j++) b[j] = *(const short8*)&sB[(wn * 64 + j * 16 + r) * 32 + q * 8];
#pragma unroll
        for (int i = 0; i < 4; i++)
#pragma unroll
            for (int j = 0; j < 4; j++)
                acc[i][j] = __builtin_amdgcn_mfma_f32_16x16x32_bf16(a[i], b[j], acc[i][j], 0, 0, 0);
    }

    const int h = nb / 3, sel = nb % 3;
#pragma unroll
    for (int i = 0; i < 4; i++) {
#pragma unroll
        for (int j = 0; j < 4; j++) {
            const int row0 = mb * 128 + wm * 64 + i * 16 + q * 4;
            const int col  = wn * 64 + j * 16 + r;
            if (sel == 2) {
                ushort4 v;
                v.x = f32_to_bf16(acc[i][j][0]);
                v.y = f32_to_bf16(acc[i][j][1]);
                v.z = f32_to_bf16(acc[i][j][2]);
                v.w = f32_to_bf16(acc[i][j][3]);
                *(ushort4*)&Vt[((size_t)h * EHEAD + col) * SEQ + row0] = v;
            } else {
                unsigned short* dst = (sel == 0) ? Q : Kb;
#pragma unroll
                for (int reg = 0; reg < 4; reg++)
                    dst[((size_t)h * SEQ + row0 + reg) * EHEAD + col] = f32_to_bf16(acc[i][j][reg]);
            }
        }
    }
}

// ---------------- fused flash attention, double-buffered K/V ----------------
// flat grid 512; XCD swizzle pins each head's 32 Q-blocks to one XCD (K/V L2-resident).
// Dynamic LDS 80KB: sQ/sP 16KB | sK dbuf 2x16KB | sV dbuf 2x16KB. One barrier/iter;
// K/V prefetch for it+1 issued right after the barrier -> vmcnt drain next iter is ~free.
__global__ __launch_bounds__(256, 2) void flash_attn(
        const unsigned short* __restrict__ Qg,
        const unsigned short* __restrict__ Kg,
        const unsigned short* __restrict__ Vtg,
        float* __restrict__ out) {
    extern __shared__ __attribute__((aligned(16))) unsigned short lds[];
    unsigned short* sQ  = lds;            // 8192 shorts (Q tile; aliased by sP after prologue)
    unsigned short* sK0 = lds + 8192;     // 2 x 8192 shorts
    unsigned short* sV0 = lds + 24576;    // 2 x 8192 shorts

    const int tid = threadIdx.x;
    const int wave = tid >> 6, lane = tid & 63;
    const int r = lane & 15, q = lane >> 4;
    const int b = blockIdx.x;
    const int h  = (b & 7) + (((b >> 3) >> 5) << 3);   // head -> XCD b%8
    const int m0 = ((b >> 3) & 31) * 64;

    const unsigned short* Qh  = Qg  + ((size_t)h * SEQ + m0) * EHEAD;
    const unsigned short* Kh0 = Kg  + (size_t)h * SEQ * EHEAD;
    const unsigned short* Vh  = Vtg + (size_t)h * EHEAD * SEQ;

    // ---- prologue: stage Q + K/V tile 0 (buffer 0) ----
#pragma unroll
    for (int c = 0; c < 4; c++)
        async_load16(Qh + (size_t)(tid >> 2) * EHEAD + c * 32 + (tid & 3) * 8,
                     sQ + c * 2048 + wave * 512);
#pragma unroll
    for (int c = 0; c < 4; c++)
        async_load16(Kh0 + (size_t)(tid >> 2) * EHEAD + c * 32 + (tid & 3) * 8,
                     sK0 + c * 2048 + wave * 512);
#pragma unroll
    for (int c = 0; c < 4; c++)
        async_load16(Vh + (size_t)((c & 1) * 64 + (tid >> 2)) * SEQ + (c >> 1) * 32 + (tid & 3) * 8,
                     sV0 + (c >> 1) * 4096 + (c & 1) * 2048 + wave * 512);
    __syncthreads();
    short8 aq[4];
#pragma unroll
    for (int k = 0; k < 4; k++)
        aq[k] = *(const short8*)&sQ[k * 2048 + (wave * 16 + r) * 32 + q * 8];
    // per-wave P region aliasing sQ: [2 tk][16 rows][40 shorts] (rows 80B, 16B-aligned)
    unsigned short* sP = sQ + wave * 1280;

    const float c1 = 0.12752405856f;   // (1/sqrt(128)) * log2(e)
    f32x4 acc_o[8] = {};
    float m_i[4] = {-1e30f, -1e30f, -1e30f, -1e30f};
    float l_i[4] = {};

    for (int it = 0; it < SEQ / 64; it++) {
        unsigned short* sKc = sK0 + (it & 1) * 8192;
        unsigned short* sVc = sV0 + (it & 1) * 8192;
        // barrier: (1) staging of current buffer (issued prev iter) drained,
        //          (2) all waves done reading the buffer we're about to overwrite.
        __syncthreads();
        if (it + 1 < SEQ / 64) {
            unsigned short* sKn = sK0 + ((it + 1) & 1) * 8192;
            unsigned short* sVn = sV0 + ((it + 1) & 1) * 8192;
            const unsigned short* Kh = Kh0 + (size_t)((it + 1) * 64) * EHEAD;
#pragma unroll
            for (int c = 0; c < 4; c++)
                async_load16(Kh + (size_t)(tid >> 2) * EHEAD + c * 32 + (tid & 3) * 8,
                             sKn + c * 2048 + wave * 512);
#pragma unroll
            for (int c = 0; c < 4; c++)
                async_load16(Vh + (size_t)((c & 1) * 64 + (tid >> 2)) * SEQ + (it + 1) * 64 + (c >> 1) * 32 + (tid & 3) * 8,
                             sVn + (c >> 1) * 4096 + (c & 1) * 2048 + wave * 512);
        }

        // ---- S = Q K^T over this 64-key tile ----
        f32x4 s[4] = {};
#pragma unroll
        for (int j = 0; j < 4; j++)
#pragma unroll
            for (int k = 0; k < 4; k++) {
                short8 bk = *(const short8*)&sKc[k * 2048 + (j * 16 + r) * 32 + q * 8];
                s[j] = __builtin_amdgcn_mfma_f32_16x16x32_bf16(aq[k], bk, s[j], 0, 0, 0);
            }

        // ---- online softmax, exp2 domain (m tracked unscaled) ----
        bool need = false;
        float alpha[4];
#pragma unroll
        for (int reg = 0; reg < 4; reg++) {
            float mx = fmaxf(fmaxf(s[0][reg], s[1][reg]), fmaxf(s[2][reg], s[3][reg]));
            mx = fmaxf(mx, __shfl_xor(mx, 1));
            mx = fmaxf(mx, __shfl_xor(mx, 2));
            mx = fmaxf(mx, __shfl_xor(mx, 4));
            mx = fmaxf(mx, __shfl_xor(mx, 8));
            float mnew = fmaxf(m_i[reg], mx);
            need |= (mnew > m_i[reg]);
            alpha[reg] = exp2f((m_i[reg] - mnew) * c1);
            m_i[reg] = mnew;
            float nb = mnew * c1;
            float rsum = 0.f;
#pragma unroll
            for (int j = 0; j < 4; j++) {
                float p = exp2f(__builtin_fmaf(s[j][reg], c1, -nb));
                s[j][reg] = p;
                rsum += p;
            }
            rsum += __shfl_xor(rsum, 1);
            rsum += __shfl_xor(rsum, 2);
            rsum += __shfl_xor(rsum, 4);
            rsum += __shfl_xor(rsum, 8);
            l_i[reg] = l_i[reg] * alpha[reg] + rsum;
        }
        if (__any(need)) {
#pragma unroll
            for (int j = 0; j < 8; j++)
#pragma unroll
                for (int reg = 0; reg < 4; reg++) acc_o[j][reg] *= alpha[reg];
        }

        // ---- P -> LDS (C-layout -> A-layout), per-wave [2][16][40] ----
#pragma unroll
        for (int j = 0; j < 4; j++)
#pragma unroll
            for (int reg = 0; reg < 4; reg++)
                sP[(j >> 1) * 640 + (q * 4 + reg) * 40 + (j & 1) * 16 + r] = f32_to_bf16(s[j][reg]);

        short8 ap[2];
#pragma unroll
        for (int tk = 0; tk < 2; tk++)
            ap[tk] = *(const short8*)&sP[tk * 640 + r * 40 + q * 8];

        // ---- O += P V ----
#pragma unroll
        for (int j = 0; j < 8; j++)
#pragma unroll
            for (int tk = 0; tk < 2; tk++) {
                short8 bv = *(const short8*)&sVc[tk * 4096 + (j * 16 + r) * 32 + q * 8];
                acc_o[j] = __builtin_amdgcn_mfma_f32_16x16x32_bf16(ap[tk], bv, acc_o[j], 0, 0, 0);
            }
    }

    // ---- epilogue: normalize + store fp32 ----
    float inv[4];
#pragma unroll
    for (int reg = 0; reg < 4; reg++) inv[reg] = 1.0f / l_i[reg];
#pragma unroll
    for (int j = 0; j < 8; j++)
#pragma unroll
        for (int reg = 0; reg < 4; reg++)
            out[(size_t)(m0 + wave * 16 + q * 4 + reg) * DMODEL + h * EHEAD + j * 16 + r] =
                acc_o[j][reg] * inv[reg];
}

extern "C" void kernel_launch(void* const* d_in, const int* in_sizes, int n_in,
                              void* d_out, int out_size, void* d_ws, size_t ws_size,
                              hipStream_t stream) {
    const float* x = (const float*)d_in[0];      // [S][D]
    const float* w = (const float*)d_in[1];      // [H][D][3E]
    float* out = (float*)d_out;                  // [S][H*E]

    char* ws = (char*)d_ws;
    unsigned short* xb = (unsigned short*)(ws);                        //  8 MB
    unsigned short* wT = (unsigned short*)(ws + 8388608);              // 24 MB
    unsigned short* Q  = (unsigned short*)(ws + 33554432);             //  8 MB
    unsigned short* Kb = (unsigned short*)(ws + 41943040);             //  8 MB
    unsigned short* Vt = (unsigned short*)(ws + 50331648);             //  8 MB

    static bool attr_set = false;
    if (!attr_set) {
        hipFuncSetAttribute((const void*)flash_attn,
                            hipFuncAttributeMaxDynamicSharedMemorySize, 81920);
        attr_set = true;
    }

    cast_x_kernel<<<SEQ * DMODEL / (256 * 4), 256, 0, stream>>>(x, xb);
    transpose_w_kernel<<<dim3(DMODEL / 64, NE3 / 64, NHEAD), 256, 0, stream>>>(w, wT);
    qkv_gemm128<<<dim3(SEQ / 128, (NHEAD * NE3) / 128), 256, 0, stream>>>(xb, wT, Q, Kb, Vt);
    flash_attn<<<512, 256, 81920, stream>>>(Q, Kb, Vt, out);
}